// Round 1
// baseline (1173.084 us; speedup 1.0000x reference)
//
#include <hip/hip_runtime.h>
#include <hip/hip_bf16.h>
#include <math.h>

#define NMAT  50000
#define NOPS  100000
#define NEDGE 512000
#define DOPR  192
#define DEAT  64

static __device__ __forceinline__ float lrelu(float x) { return x > 0.f ? x : 0.2f * x; }
static __device__ __forceinline__ float elu(float x)   { return x > 0.f ? x : expm1f(x); }

// ---------------- C[M][128] = A[M][K] @ B[K][128], fp32 register-tiled ----------------
template<int K>
__launch_bounds__(256)
__global__ void gemm_rt(const float* __restrict__ A, const float* __restrict__ B,
                        float* __restrict__ C, int M)
{
    __shared__ float As[32][132];   // [k][row], pad->conflict-free b128 reads
    __shared__ float Bs[32][128];   // [k][col]
    const int t  = threadIdx.x;
    const int tr = t >> 4;          // wave has 4 distinct tr -> rows 8*tr..8*tr+7
    const int tc = t & 15;          // cols tc*4..+3 and 64+tc*4..+3 (split -> bank-friendly)
    const int row0 = blockIdx.x * 128;
    const int c0 = tc * 4, c1 = 64 + tc * 4;

    float acc[8][8];
#pragma unroll
    for (int i = 0; i < 8; ++i)
#pragma unroll
        for (int j = 0; j < 8; ++j) acc[i][j] = 0.f;

    for (int k0 = 0; k0 < K; k0 += 32) {
#pragma unroll
        for (int it = 0; it < 4; ++it) {            // stage A: 128 rows x 32 k
            int q  = t + 256 * it;
            int r  = q >> 3;
            int kk = (q & 7) * 4;
            int gr = row0 + r; if (gr >= M) gr = M - 1;   // clamp (stores are guarded)
            float4 v = *reinterpret_cast<const float4*>(A + (size_t)gr * K + k0 + kk);
            As[kk + 0][r] = v.x; As[kk + 1][r] = v.y;
            As[kk + 2][r] = v.z; As[kk + 3][r] = v.w;
        }
#pragma unroll
        for (int it = 0; it < 4; ++it) {            // stage B: 32 k x 128 cols
            int q  = t + 256 * it;
            int kk = q >> 5;
            int cc = (q & 31) * 4;
            *reinterpret_cast<float4*>(&Bs[kk][cc]) =
                *reinterpret_cast<const float4*>(B + (size_t)(k0 + kk) * 128 + cc);
        }
        __syncthreads();
#pragma unroll 8
        for (int k = 0; k < 32; ++k) {
            float4 a0 = *reinterpret_cast<const float4*>(&As[k][8 * tr]);
            float4 a1 = *reinterpret_cast<const float4*>(&As[k][8 * tr + 4]);
            float4 b0 = *reinterpret_cast<const float4*>(&Bs[k][c0]);
            float4 b1 = *reinterpret_cast<const float4*>(&Bs[k][c1]);
            float av[8] = {a0.x, a0.y, a0.z, a0.w, a1.x, a1.y, a1.z, a1.w};
            float bv[8] = {b0.x, b0.y, b0.z, b0.w, b1.x, b1.y, b1.z, b1.w};
#pragma unroll
            for (int i = 0; i < 8; ++i)
#pragma unroll
                for (int j = 0; j < 8; ++j) acc[i][j] += av[i] * bv[j];
        }
        __syncthreads();
    }
#pragma unroll
    for (int i = 0; i < 8; ++i) {
        int gr = row0 + 8 * tr + i;
        if (gr < M) {
            float4 o0 = {acc[i][0], acc[i][1], acc[i][2], acc[i][3]};
            float4 o1 = {acc[i][4], acc[i][5], acc[i][6], acc[i][7]};
            *reinterpret_cast<float4*>(C + (size_t)gr * 128 + c0) = o0;
            *reinterpret_cast<float4*>(C + (size_t)gr * 128 + c1) = o1;
        }
    }
}

// ---------------- self-attention scores: s[i] = lrelu(m[i] . (a[:128]+a[128:])) ----------------
__launch_bounds__(256)
__global__ void self_att_kernel(const float* __restrict__ m, const float* __restrict__ att_self,
                                float* __restrict__ s)
{
    int wid  = (int)((blockIdx.x * 256 + threadIdx.x) >> 6);   // one wave per row
    int lane = threadIdx.x & 63;
    if (wid >= NMAT) return;
    float2 mv = *reinterpret_cast<const float2*>(m + (size_t)wid * 128 + lane * 2);
    float a0 = att_self[lane * 2]     + att_self[128 + lane * 2];
    float a1 = att_self[lane * 2 + 1] + att_self[128 + lane * 2 + 1];
    float p = mv.x * a0 + mv.y * a1;
#pragma unroll
    for (int off = 1; off < 64; off <<= 1) p += __shfl_xor(p, off, 64);
    if (lane == 0) s[wid] = lrelu(p);
}

// ---------------- edge pass: ops_e = op_proj[src] + edge_attr @ W_op[192:] ----------------
// PHASE 0: cross scores -> s[NMAT+e].  PHASE 1: agg[dst] += w * ops_e (recompute, atomics).
template<int PHASE>
__launch_bounds__(256)
__global__ void edge_pass(const float* __restrict__ op_proj, const float* __restrict__ m,
                          const float* __restrict__ edge_attr,
                          const int* __restrict__ esrc, const int* __restrict__ edst,
                          const float* __restrict__ W_op, const float* __restrict__ att_cross,
                          float* __restrict__ s, const float* __restrict__ stats,
                          float* __restrict__ agg)
{
    __shared__ float Wb[64][128];   // W_op rows 192..255
    __shared__ float ea[64][68];    // 64 edges x 64 attrs (pad 68: 16B-aligned rows, bank spread)
    const int t  = threadIdx.x;
    const int tc = t & 15;
    const int eg = t >> 4;
    const int c0 = tc * 4, c1 = 64 + tc * 4;

#pragma unroll
    for (int it = 0; it < 8; ++it) {
        int q  = t + 256 * it;
        int kk = q >> 5, cc = (q & 31) * 4;
        *reinterpret_cast<float4*>(&Wb[kk][cc]) =
            *reinterpret_cast<const float4*>(W_op + (size_t)(DOPR + kk) * 128 + cc);
    }
    float c0r[8], c1r[8];
#pragma unroll
    for (int j = 0; j < 4; ++j) {
        c0r[j]     = att_cross[c0 + j];
        c0r[4 + j] = att_cross[c1 + j];
        c1r[j]     = att_cross[128 + c0 + j];
        c1r[4 + j] = att_cross[128 + c1 + j];
    }
    float Mx = 0.f, invS = 0.f;
    if (PHASE == 1) { Mx = stats[0]; invS = stats[1]; }

    for (int it2 = 0; it2 < 8; ++it2) {
        const int e0 = blockIdx.x * 512 + it2 * 64;
        if (e0 >= NEDGE) break;
        __syncthreads();                       // previous iter's ea readers done
#pragma unroll
        for (int it = 0; it < 4; ++it) {       // stage 64 edge_attr rows
            int q = t + 256 * it;
            int r = q >> 4, kk = (q & 15) * 4;
            *reinterpret_cast<float4*>(&ea[r][kk]) =
                *reinterpret_cast<const float4*>(edge_attr + (size_t)(e0 + r) * DEAT + kk);
        }
        __syncthreads();

        float acc[4][8];
        int   eidx[4], dst[4];
#pragma unroll
        for (int u = 0; u < 4; ++u) {
            int e   = e0 + eg + 16 * u;
            eidx[u] = e;
            int sv  = esrc[e];
            dst[u]  = edst[e];
            const float* oprow = op_proj + (size_t)sv * 128;
            float4 p0 = *reinterpret_cast<const float4*>(oprow + c0);
            float4 p1 = *reinterpret_cast<const float4*>(oprow + c1);
            acc[u][0] = p0.x; acc[u][1] = p0.y; acc[u][2] = p0.z; acc[u][3] = p0.w;
            acc[u][4] = p1.x; acc[u][5] = p1.y; acc[u][6] = p1.z; acc[u][7] = p1.w;
        }
#pragma unroll 4
        for (int k = 0; k < 64; ++k) {
            float4 b0 = *reinterpret_cast<const float4*>(&Wb[k][c0]);
            float4 b1 = *reinterpret_cast<const float4*>(&Wb[k][c1]);
            float bv[8] = {b0.x, b0.y, b0.z, b0.w, b1.x, b1.y, b1.z, b1.w};
#pragma unroll
            for (int u = 0; u < 4; ++u) {
                float a = ea[eg + 16 * u][k];
#pragma unroll
                for (int j = 0; j < 8; ++j) acc[u][j] += a * bv[j];
            }
        }

        if (PHASE == 0) {
#pragma unroll
            for (int u = 0; u < 4; ++u) {
                const float* mrow = m + (size_t)dst[u] * 128;
                float4 m0 = *reinterpret_cast<const float4*>(mrow + c0);
                float4 m1 = *reinterpret_cast<const float4*>(mrow + c1);
                float mv[8] = {m0.x, m0.y, m0.z, m0.w, m1.x, m1.y, m1.z, m1.w};
                float p = 0.f;
#pragma unroll
                for (int j = 0; j < 8; ++j) p += mv[j] * c0r[j] + acc[u][j] * c1r[j];
#pragma unroll
                for (int off = 1; off < 16; off <<= 1) p += __shfl_xor(p, off, 64);
                if (tc == 0) s[NMAT + eidx[u]] = lrelu(p);
            }
        } else {
#pragma unroll
            for (int u = 0; u < 4; ++u) {
                float w = expf(s[NMAT + eidx[u]] - Mx) * invS;
                float* arow = agg + (size_t)dst[u] * 128;
#pragma unroll
                for (int j = 0; j < 4; ++j) atomicAdd(arow + c0 + j, w * acc[u][j]);
#pragma unroll
                for (int j = 0; j < 4; ++j) atomicAdd(arow + c1 + j, w * acc[u][4 + j]);
            }
        }
    }
}

// ---------------- global softmax reduction (online max+sumexp merge) ----------------
__launch_bounds__(256)
__global__ void softmax_red1(const float* __restrict__ s, float* __restrict__ part)
{
    const int n = NMAT + NEDGE;
    float mx = -INFINITY, sm = 0.f;
    for (int i = blockIdx.x * 256 + threadIdx.x; i < n; i += gridDim.x * 256) {
        float x = s[i];
        if (x > mx) { sm = sm * expf(mx - x) + 1.f; mx = x; }
        else        { sm += expf(x - mx); }
    }
#pragma unroll
    for (int off = 1; off < 64; off <<= 1) {
        float om = __shfl_xor(mx, off, 64);
        float os = __shfl_xor(sm, off, 64);
        float nm = fmaxf(mx, om);
        sm = sm * expf(mx - nm) + os * expf(om - nm);
        mx = nm;
    }
    __shared__ float wm[4], wsum[4];
    int lane = threadIdx.x & 63, wv = threadIdx.x >> 6;
    if (lane == 0) { wm[wv] = mx; wsum[wv] = sm; }
    __syncthreads();
    if (threadIdx.x == 0) {
        float M = wm[0], S = wsum[0];
        for (int i = 1; i < 4; ++i) {
            float nm = fmaxf(M, wm[i]);
            S = S * expf(M - nm) + wsum[i] * expf(wm[i] - nm);
            M = nm;
        }
        part[2 * blockIdx.x]     = M;
        part[2 * blockIdx.x + 1] = S;
    }
}

__launch_bounds__(256)
__global__ void softmax_red2(const float* __restrict__ part, float* __restrict__ stats)
{
    float mx = -INFINITY, sm = 0.f;
    for (int i = threadIdx.x; i < 1024; i += 256) {
        float M = part[2 * i], S = part[2 * i + 1];
        float nm = fmaxf(mx, M);
        sm = sm * expf(mx - nm) + S * expf(M - nm);
        mx = nm;
    }
#pragma unroll
    for (int off = 1; off < 64; off <<= 1) {
        float om = __shfl_xor(mx, off, 64);
        float os = __shfl_xor(sm, off, 64);
        float nm = fmaxf(mx, om);
        sm = sm * expf(mx - nm) + os * expf(om - nm);
        mx = nm;
    }
    __shared__ float wm[4], wsum[4];
    int lane = threadIdx.x & 63, wv = threadIdx.x >> 6;
    if (lane == 0) { wm[wv] = mx; wsum[wv] = sm; }
    __syncthreads();
    if (threadIdx.x == 0) {
        float M = wm[0], S = wsum[0];
        for (int i = 1; i < 4; ++i) {
            float nm = fmaxf(M, wm[i]);
            S = S * expf(M - nm) + wsum[i] * expf(wm[i] - nm);
            M = nm;
        }
        stats[0] = M;
        stats[1] = 1.f / S;
    }
}

// ---------------- out = elu(norm_self * m + agg) ----------------
__launch_bounds__(256)
__global__ void final_kernel(const float* __restrict__ m, const float* __restrict__ agg,
                             const float* __restrict__ s, const float* __restrict__ stats,
                             float* __restrict__ out)
{
    int q = blockIdx.x * 256 + threadIdx.x;       // float4 id
    if (q >= NMAT * 32) return;
    int row = q >> 5;
    int cc  = (q & 31) * 4;
    float ns = expf(s[row] - stats[0]) * stats[1];
    float4 mv = *reinterpret_cast<const float4*>(m   + (size_t)row * 128 + cc);
    float4 av = *reinterpret_cast<const float4*>(agg + (size_t)row * 128 + cc);
    float4 r;
    r.x = elu(ns * mv.x + av.x);
    r.y = elu(ns * mv.y + av.y);
    r.z = elu(ns * mv.z + av.z);
    r.w = elu(ns * mv.w + av.w);
    *reinterpret_cast<float4*>(out + (size_t)row * 128 + cc) = r;
}

extern "C" void kernel_launch(void* const* d_in, const int* in_sizes, int n_in,
                              void* d_out, int out_size, void* d_ws, size_t ws_size,
                              hipStream_t stream)
{
    const float* materials  = (const float*)d_in[0];
    const float* operations = (const float*)d_in[1];
    const float* edge_attr  = (const float*)d_in[2];
    const int*   esrc       = (const int*)d_in[3];
    const int*   edst       = (const int*)d_in[4];
    const float* W_mat      = (const float*)d_in[5];
    const float* W_op       = (const float*)d_in[6];
    const float* att_self   = (const float*)d_in[7];
    const float* att_cross  = (const float*)d_in[8];
    float* out = (float*)d_out;

    // workspace layout (fp32): ~105 MB total
    float* ws      = (float*)d_ws;
    float* m_buf   = ws;                                   // NMAT*128
    float* op_proj = m_buf + (size_t)NMAT * 128;           // NOPS*128
    float* s_buf   = op_proj + (size_t)NOPS * 128;         // NMAT+NEDGE
    float* agg     = s_buf + (NMAT + NEDGE);               // NMAT*128
    float* part    = agg + (size_t)NMAT * 128;             // 2048
    float* stats   = part + 2048;                          // 2

    hipMemsetAsync(agg, 0, (size_t)NMAT * 128 * sizeof(float), stream);

    gemm_rt<128><<<(NMAT + 127) / 128, 256, 0, stream>>>(materials, W_mat, m_buf, NMAT);
    self_att_kernel<<<(NMAT + 3) / 4, 256, 0, stream>>>(m_buf, att_self, s_buf);
    gemm_rt<192><<<(NOPS + 127) / 128, 256, 0, stream>>>(operations, W_op, op_proj, NOPS);
    edge_pass<0><<<NEDGE / 512, 256, 0, stream>>>(op_proj, m_buf, edge_attr, esrc, edst,
                                                  W_op, att_cross, s_buf, stats, agg);
    softmax_red1<<<1024, 256, 0, stream>>>(s_buf, part);
    softmax_red2<<<1, 256, 0, stream>>>(part, stats);
    edge_pass<1><<<NEDGE / 512, 256, 0, stream>>>(op_proj, m_buf, edge_attr, esrc, edst,
                                                  W_op, att_cross, s_buf, stats, agg);
    final_kernel<<<(NMAT * 32 + 255) / 256, 256, 0, stream>>>(m_buf, agg, s_buf, stats, out);
}

// Round 2
// 585.609 us; speedup vs baseline: 2.0032x; 2.0032x over previous
//
#include <hip/hip_runtime.h>
#include <hip/hip_bf16.h>
#include <math.h>

#define NMAT  50000
#define NOPS  100000
#define NEDGE 512000
#define DOPR  192
#define DEAT  64

static __device__ __forceinline__ float lrelu(float x) { return x > 0.f ? x : 0.2f * x; }
static __device__ __forceinline__ float elu(float x)   { return x > 0.f ? x : expm1f(x); }

// ---------------- C[M][128] = A[M][K] @ B[K][128], fp32 register-tiled ----------------
template<int K>
__launch_bounds__(256)
__global__ void gemm_rt(const float* __restrict__ A, const float* __restrict__ B,
                        float* __restrict__ C, int M)
{
    __shared__ float As[32][132];
    __shared__ float Bs[32][128];
    const int t  = threadIdx.x;
    const int tr = t >> 4;
    const int tc = t & 15;
    const int row0 = blockIdx.x * 128;
    const int c0 = tc * 4, c1 = 64 + tc * 4;

    float acc[8][8];
#pragma unroll
    for (int i = 0; i < 8; ++i)
#pragma unroll
        for (int j = 0; j < 8; ++j) acc[i][j] = 0.f;

    for (int k0 = 0; k0 < K; k0 += 32) {
#pragma unroll
        for (int it = 0; it < 4; ++it) {
            int q  = t + 256 * it;
            int r  = q >> 3;
            int kk = (q & 7) * 4;
            int gr = row0 + r; if (gr >= M) gr = M - 1;
            float4 v = *reinterpret_cast<const float4*>(A + (size_t)gr * K + k0 + kk);
            As[kk + 0][r] = v.x; As[kk + 1][r] = v.y;
            As[kk + 2][r] = v.z; As[kk + 3][r] = v.w;
        }
#pragma unroll
        for (int it = 0; it < 4; ++it) {
            int q  = t + 256 * it;
            int kk = q >> 5;
            int cc = (q & 31) * 4;
            *reinterpret_cast<float4*>(&Bs[kk][cc]) =
                *reinterpret_cast<const float4*>(B + (size_t)(k0 + kk) * 128 + cc);
        }
        __syncthreads();
#pragma unroll 8
        for (int k = 0; k < 32; ++k) {
            float4 a0 = *reinterpret_cast<const float4*>(&As[k][8 * tr]);
            float4 a1 = *reinterpret_cast<const float4*>(&As[k][8 * tr + 4]);
            float4 b0 = *reinterpret_cast<const float4*>(&Bs[k][c0]);
            float4 b1 = *reinterpret_cast<const float4*>(&Bs[k][c1]);
            float av[8] = {a0.x, a0.y, a0.z, a0.w, a1.x, a1.y, a1.z, a1.w};
            float bv[8] = {b0.x, b0.y, b0.z, b0.w, b1.x, b1.y, b1.z, b1.w};
#pragma unroll
            for (int i = 0; i < 8; ++i)
#pragma unroll
                for (int j = 0; j < 8; ++j) acc[i][j] += av[i] * bv[j];
        }
        __syncthreads();
    }
#pragma unroll
    for (int i = 0; i < 8; ++i) {
        int gr = row0 + 8 * tr + i;
        if (gr < M) {
            float4 o0 = {acc[i][0], acc[i][1], acc[i][2], acc[i][3]};
            float4 o1 = {acc[i][4], acc[i][5], acc[i][6], acc[i][7]};
            *reinterpret_cast<float4*>(C + (size_t)gr * 128 + c0) = o0;
            *reinterpret_cast<float4*>(C + (size_t)gr * 128 + c1) = o1;
        }
    }
}

// ---------------- tiny prep: asum = as[:128]+as[128:], wv = Wb @ c1 ----------------
__launch_bounds__(256)
__global__ void k_prep(const float* __restrict__ att_self, const float* __restrict__ att_cross,
                       const float* __restrict__ W_op, float* __restrict__ asum,
                       float* __restrict__ wv)
{
    int t = threadIdx.x;
    if (t < 128) asum[t] = att_self[t] + att_self[128 + t];
    if (t < 64) {
        float p = 0.f;
        const float* wr = W_op + (size_t)(DOPR + t) * 128;
#pragma unroll 16
        for (int j = 0; j < 128; ++j) p += wr[j] * att_cross[128 + j];
        wv[t] = p;
    }
}

// ---------------- per-row dots: dm = m.c0, s_self = lrelu(m.asum) ----------------
__launch_bounds__(256)
__global__ void k_rowdots_mat(const float* __restrict__ m, const float* __restrict__ att_cross,
                              const float* __restrict__ asum, float* __restrict__ dm,
                              float* __restrict__ s)
{
    int wid  = (int)((blockIdx.x * 256 + threadIdx.x) >> 6);
    int lane = threadIdx.x & 63;
    if (wid >= NMAT) return;
    float2 mv = *reinterpret_cast<const float2*>(m + (size_t)wid * 128 + lane * 2);
    float2 cv = *reinterpret_cast<const float2*>(att_cross + lane * 2);
    float2 av = *reinterpret_cast<const float2*>(asum + lane * 2);
    float pc = mv.x * cv.x + mv.y * cv.y;
    float pa = mv.x * av.x + mv.y * av.y;
#pragma unroll
    for (int off = 1; off < 64; off <<= 1) {
        pc += __shfl_xor(pc, off, 64);
        pa += __shfl_xor(pa, off, 64);
    }
    if (lane == 0) { dm[wid] = pc; s[wid] = lrelu(pa); }
}

// ---------------- per-row dots: dop = op_proj . c1 ----------------
__launch_bounds__(256)
__global__ void k_rowdots_op(const float* __restrict__ op_proj, const float* __restrict__ att_cross,
                             float* __restrict__ dop)
{
    int wid  = (int)((blockIdx.x * 256 + threadIdx.x) >> 6);
    int lane = threadIdx.x & 63;
    if (wid >= NOPS) return;
    float2 pv = *reinterpret_cast<const float2*>(op_proj + (size_t)wid * 128 + lane * 2);
    float2 cv = *reinterpret_cast<const float2*>(att_cross + 128 + lane * 2);
    float p = pv.x * cv.x + pv.y * cv.y;
#pragma unroll
    for (int off = 1; off < 64; off <<= 1) p += __shfl_xor(p, off, 64);
    if (lane == 0) dop[wid] = p;
}

// ---------------- edge scores + dst histogram: s[NMAT+e] = lrelu(dm[dst]+dop[src]+ea.wv) ----
__launch_bounds__(256)
__global__ void k_edge_score(const float* __restrict__ edge_attr,
                             const int* __restrict__ esrc, const int* __restrict__ edst,
                             const float* __restrict__ dm, const float* __restrict__ dop,
                             const float* __restrict__ wv, float* __restrict__ s,
                             int* __restrict__ cnt)
{
    int t = threadIdx.x;
    int g = t >> 4, q = t & 15;
    float4 wvq = *reinterpret_cast<const float4*>(wv + q * 4);
#pragma unroll
    for (int u = 0; u < 8; ++u) {
        int e = blockIdx.x * 128 + u * 16 + g;     // consecutive groups -> contiguous rows
        float4 av = *reinterpret_cast<const float4*>(edge_attr + (size_t)e * DEAT + q * 4);
        float p = av.x * wvq.x + av.y * wvq.y + av.z * wvq.z + av.w * wvq.w;
#pragma unroll
        for (int off = 1; off < 16; off <<= 1) p += __shfl_xor(p, off, 16);
        if (q == 0) {
            int d = edst[e];
            s[NMAT + e] = lrelu(p + dm[d] + dop[esrc[e]]);
            atomicAdd(&cnt[d], 1);
        }
    }
}

// ---------------- exclusive scan of cnt[NMAT] -> rowptr, cursor ----------------
__launch_bounds__(1024)
__global__ void k_scan(const int* __restrict__ cnt, int* __restrict__ rowptr,
                       int* __restrict__ cursor)
{
    __shared__ int sdata[1024];
    const int t = threadIdx.x;
    const int CH = 49;                               // 1024*49 = 50176 >= 50000
    int base = t * CH;
    int lsum = 0;
#pragma unroll
    for (int j = 0; j < CH; ++j) {
        int idx = base + j;
        if (idx < NMAT) lsum += cnt[idx];
    }
    sdata[t] = lsum;
    __syncthreads();
    for (int off = 1; off < 1024; off <<= 1) {
        int v = (t >= off) ? sdata[t - off] : 0;
        __syncthreads();
        sdata[t] += v;
        __syncthreads();
    }
    int run = sdata[t] - lsum;                       // exclusive base
#pragma unroll
    for (int j = 0; j < CH; ++j) {
        int idx = base + j;
        if (idx < NMAT) {
            rowptr[idx] = run;
            cursor[idx] = run;
            run += cnt[idx];
        }
    }
    if (t == 1023) rowptr[NMAT] = NEDGE;
}

// ---------------- CSR fill ----------------
__launch_bounds__(256)
__global__ void k_fill(const int* __restrict__ edst, int* __restrict__ cursor,
                       int* __restrict__ eid)
{
    int e = blockIdx.x * 256 + threadIdx.x;
    if (e >= NEDGE) return;
    int pos = atomicAdd(&cursor[edst[e]], 1);
    eid[pos] = e;
}

// ---------------- global softmax reduction (online max+sumexp merge) ----------------
__launch_bounds__(256)
__global__ void softmax_red1(const float* __restrict__ s, float* __restrict__ part)
{
    const int n = NMAT + NEDGE;
    float mx = -INFINITY, sm = 0.f;
    for (int i = blockIdx.x * 256 + threadIdx.x; i < n; i += gridDim.x * 256) {
        float x = s[i];
        if (x > mx) { sm = sm * expf(mx - x) + 1.f; mx = x; }
        else        { sm += expf(x - mx); }
    }
#pragma unroll
    for (int off = 1; off < 64; off <<= 1) {
        float om = __shfl_xor(mx, off, 64);
        float os = __shfl_xor(sm, off, 64);
        float nm = fmaxf(mx, om);
        sm = sm * expf(mx - nm) + os * expf(om - nm);
        mx = nm;
    }
    __shared__ float wm[4], wsum[4];
    int lane = threadIdx.x & 63, wv = threadIdx.x >> 6;
    if (lane == 0) { wm[wv] = mx; wsum[wv] = sm; }
    __syncthreads();
    if (threadIdx.x == 0) {
        float M = wm[0], S = wsum[0];
        for (int i = 1; i < 4; ++i) {
            float nm = fmaxf(M, wm[i]);
            S = S * expf(M - nm) + wsum[i] * expf(wm[i] - nm);
            M = nm;
        }
        part[2 * blockIdx.x]     = M;
        part[2 * blockIdx.x + 1] = S;
    }
}

__launch_bounds__(256)
__global__ void softmax_red2(const float* __restrict__ part, float* __restrict__ stats)
{
    float mx = -INFINITY, sm = 0.f;
    for (int i = threadIdx.x; i < 1024; i += 256) {
        float M = part[2 * i], S = part[2 * i + 1];
        float nm = fmaxf(mx, M);
        sm = sm * expf(mx - nm) + S * expf(M - nm);
        mx = nm;
    }
#pragma unroll
    for (int off = 1; off < 64; off <<= 1) {
        float om = __shfl_xor(mx, off, 64);
        float os = __shfl_xor(sm, off, 64);
        float nm = fmaxf(mx, om);
        sm = sm * expf(mx - nm) + os * expf(om - nm);
        mx = nm;
    }
    __shared__ float wm[4], wsum[4];
    int lane = threadIdx.x & 63, wv = threadIdx.x >> 6;
    if (lane == 0) { wm[wv] = mx; wsum[wv] = sm; }
    __syncthreads();
    if (threadIdx.x == 0) {
        float M = wm[0], S = wsum[0];
        for (int i = 1; i < 4; ++i) {
            float nm = fmaxf(M, wm[i]);
            S = S * expf(M - nm) + wsum[i] * expf(wm[i] - nm);
            M = nm;
        }
        stats[0] = M;
        stats[1] = 1.f / S;
    }
}

// ---------------- CSR aggregate + fused epilogue ----------------
// wave per material: ap = sum w*op_proj[src], aw = sum w*ea_e ; out = elu(ns*m + ap + aw@Wb)
__launch_bounds__(256)
__global__ void k_agg(const float* __restrict__ op_proj, const float* __restrict__ m,
                      const float* __restrict__ edge_attr, const int* __restrict__ esrc,
                      const float* __restrict__ W_op, const float* __restrict__ s,
                      const float* __restrict__ stats, const int* __restrict__ rowptr,
                      const int* __restrict__ eid, float* __restrict__ out)
{
    __shared__ float WbL[64][128];                   // 32 KB
    const int t = threadIdx.x;
#pragma unroll
    for (int it = 0; it < 8; ++it) {                 // stage Wb = W_op rows 192..255
        int q  = t + 256 * it;
        int kk = q >> 5, cc = (q & 31) * 4;
        *reinterpret_cast<float4*>(&WbL[kk][cc]) =
            *reinterpret_cast<const float4*>(W_op + (size_t)(DOPR + kk) * 128 + cc);
    }
    __syncthreads();

    const int w = t >> 6, lane = t & 63;
    const int mid = blockIdx.x * 4 + w;
    const float Mx = stats[0], invS = stats[1];
    const int beg = rowptr[mid], end = rowptr[mid + 1];

    float ap0 = 0.f, ap1 = 0.f, aw = 0.f;
    for (int idx = beg; idx < end; ++idx) {
        int e   = eid[idx];
        int src = esrc[e];
        float wgt = expf(s[NMAT + e] - Mx) * invS;
        const float* pr = op_proj + (size_t)src * 128;
        ap0 += wgt * pr[lane];
        ap1 += wgt * pr[64 + lane];
        aw  += wgt * edge_attr[(size_t)e * DEAT + lane];
    }
    float acc0 = ap0, acc1 = ap1;
#pragma unroll
    for (int k = 0; k < 64; ++k) {
        float a = __shfl(aw, k, 64);
        acc0 += a * WbL[k][lane];
        acc1 += a * WbL[k][64 + lane];
    }
    float ns = expf(s[mid] - Mx) * invS;
    const float* mr = m + (size_t)mid * 128;
    out[(size_t)mid * 128 + lane]      = elu(ns * mr[lane]      + acc0);
    out[(size_t)mid * 128 + 64 + lane] = elu(ns * mr[64 + lane] + acc1);
}

extern "C" void kernel_launch(void* const* d_in, const int* in_sizes, int n_in,
                              void* d_out, int out_size, void* d_ws, size_t ws_size,
                              hipStream_t stream)
{
    const float* materials  = (const float*)d_in[0];
    const float* operations = (const float*)d_in[1];
    const float* edge_attr  = (const float*)d_in[2];
    const int*   esrc       = (const int*)d_in[3];
    const int*   edst       = (const int*)d_in[4];
    const float* W_mat      = (const float*)d_in[5];
    const float* W_op       = (const float*)d_in[6];
    const float* att_self   = (const float*)d_in[7];
    const float* att_cross  = (const float*)d_in[8];
    float* out = (float*)d_out;

    // workspace layout (~83 MB)
    float* ws      = (float*)d_ws;
    float* m_buf   = ws;                                   // 6,400,000
    float* op_proj = m_buf + (size_t)NMAT * 128;           // 12,800,000
    float* s_buf   = op_proj + (size_t)NOPS * 128;         // 562,000
    float* dm      = s_buf + (NMAT + NEDGE);               // 50,000
    float* dop     = dm + NMAT;                            // 100,000
    float* asum    = dop + NOPS;                           // 128
    float* wv      = asum + 128;                           // 64
    float* part    = wv + 64;                              // 2048
    float* stats   = part + 2048;                          // 2
    int*   cnt     = (int*)(stats + 2);                    // 50,000
    int*   rowptr  = cnt + NMAT;                           // 50,001
    int*   cursor  = rowptr + NMAT + 1;                    // 50,000
    int*   eid     = cursor + NMAT;                        // 512,000

    hipMemsetAsync(cnt, 0, NMAT * sizeof(int), stream);

    k_prep<<<1, 256, 0, stream>>>(att_self, att_cross, W_op, asum, wv);
    gemm_rt<128><<<(NMAT + 127) / 128, 256, 0, stream>>>(materials, W_mat, m_buf, NMAT);
    gemm_rt<192><<<(NOPS + 127) / 128, 256, 0, stream>>>(operations, W_op, op_proj, NOPS);
    k_rowdots_mat<<<NMAT / 4, 256, 0, stream>>>(m_buf, att_cross, asum, dm, s_buf);
    k_rowdots_op<<<NOPS / 4, 256, 0, stream>>>(op_proj, att_cross, dop);
    k_edge_score<<<NEDGE / 128, 256, 0, stream>>>(edge_attr, esrc, edst, dm, dop, wv,
                                                  s_buf, cnt);
    k_scan<<<1, 1024, 0, stream>>>(cnt, rowptr, cursor);
    k_fill<<<NEDGE / 256, 256, 0, stream>>>(edst, cursor, eid);
    softmax_red1<<<1024, 256, 0, stream>>>(s_buf, part);
    softmax_red2<<<1, 256, 0, stream>>>(part, stats);
    k_agg<<<NMAT / 4, 256, 0, stream>>>(op_proj, m_buf, edge_attr, esrc, W_op,
                                        s_buf, stats, rowptr, eid, out);
}

// Round 3
// 489.756 us; speedup vs baseline: 2.3952x; 1.1957x over previous
//
#include <hip/hip_runtime.h>
#include <hip/hip_bf16.h>
#include <math.h>

#define NMAT  50000
#define NOPS  100000
#define NEDGE 512000
#define DOPR  192
#define DEAT  64

static __device__ __forceinline__ float lrelu(float x) { return x > 0.f ? x : 0.2f * x; }
static __device__ __forceinline__ float elu(float x)   { return x > 0.f ? x : expm1f(x); }
static __device__ __forceinline__ unsigned short f2bf(float x) {
    unsigned int b = __float_as_uint(x);
    return (unsigned short)((b + 0x7fffu + ((b >> 16) & 1u)) >> 16);   // RNE
}
static __device__ __forceinline__ float bflo(unsigned int u) { return __uint_as_float(u << 16); }
static __device__ __forceinline__ float bfhi(unsigned int u) { return __uint_as_float(u & 0xffff0000u); }

// ---------------- C[M][128] = A[M][K] @ B[K][128], fp32 register-tiled ----------------
// MODE 1 (materials): write Cf fp32; d1[r]=acc.v1 (dm), d2[r]=lrelu(acc.v2) (s_self)
// MODE 2 (ops):       write Cb bf16; d1[r]=acc.v1 (dop)
template<int K, int MODE>
__launch_bounds__(256)
__global__ void gemm_rt(const float* __restrict__ A, const float* __restrict__ B,
                        float* __restrict__ Cf, unsigned short* __restrict__ Cb,
                        const float* __restrict__ v1, const float* __restrict__ v2,
                        float* __restrict__ d1, float* __restrict__ d2, int M)
{
    __shared__ float As[32][132];
    __shared__ float Bs[32][128];
    const int t  = threadIdx.x;
    const int tr = t >> 4;
    const int tc = t & 15;
    const int row0 = blockIdx.x * 128;
    const int c0 = tc * 4, c1 = 64 + tc * 4;

    float acc[8][8];
#pragma unroll
    for (int i = 0; i < 8; ++i)
#pragma unroll
        for (int j = 0; j < 8; ++j) acc[i][j] = 0.f;

    for (int k0 = 0; k0 < K; k0 += 32) {
#pragma unroll
        for (int it = 0; it < 4; ++it) {
            int q  = t + 256 * it;
            int r  = q >> 3;
            int kk = (q & 7) * 4;
            int gr = row0 + r; if (gr >= M) gr = M - 1;
            float4 v = *reinterpret_cast<const float4*>(A + (size_t)gr * K + k0 + kk);
            As[kk + 0][r] = v.x; As[kk + 1][r] = v.y;
            As[kk + 2][r] = v.z; As[kk + 3][r] = v.w;
        }
#pragma unroll
        for (int it = 0; it < 4; ++it) {
            int q  = t + 256 * it;
            int kk = q >> 5;
            int cc = (q & 31) * 4;
            *reinterpret_cast<float4*>(&Bs[kk][cc]) =
                *reinterpret_cast<const float4*>(B + (size_t)(k0 + kk) * 128 + cc);
        }
        __syncthreads();
#pragma unroll 8
        for (int k = 0; k < 32; ++k) {
            float4 a0 = *reinterpret_cast<const float4*>(&As[k][8 * tr]);
            float4 a1 = *reinterpret_cast<const float4*>(&As[k][8 * tr + 4]);
            float4 b0 = *reinterpret_cast<const float4*>(&Bs[k][c0]);
            float4 b1 = *reinterpret_cast<const float4*>(&Bs[k][c1]);
            float av[8] = {a0.x, a0.y, a0.z, a0.w, a1.x, a1.y, a1.z, a1.w};
            float bv[8] = {b0.x, b0.y, b0.z, b0.w, b1.x, b1.y, b1.z, b1.w};
#pragma unroll
            for (int i = 0; i < 8; ++i)
#pragma unroll
                for (int j = 0; j < 8; ++j) acc[i][j] += av[i] * bv[j];
        }
        __syncthreads();
    }

    float v1c[8], v2c[8];
#pragma unroll
    for (int j = 0; j < 4; ++j) {
        v1c[j] = v1[c0 + j]; v1c[4 + j] = v1[c1 + j];
        if (MODE == 1) { v2c[j] = v2[c0 + j]; v2c[4 + j] = v2[c1 + j]; }
    }

#pragma unroll
    for (int i = 0; i < 8; ++i) {
        int gr = row0 + 8 * tr + i;
        bool ok = gr < M;
        if (MODE == 1 && ok) {
            float4 o0 = {acc[i][0], acc[i][1], acc[i][2], acc[i][3]};
            float4 o1 = {acc[i][4], acc[i][5], acc[i][6], acc[i][7]};
            *reinterpret_cast<float4*>(Cf + (size_t)gr * 128 + c0) = o0;
            *reinterpret_cast<float4*>(Cf + (size_t)gr * 128 + c1) = o1;
        }
        if (MODE == 2 && ok) {
            ushort4 b0 = {f2bf(acc[i][0]), f2bf(acc[i][1]), f2bf(acc[i][2]), f2bf(acc[i][3])};
            ushort4 b1 = {f2bf(acc[i][4]), f2bf(acc[i][5]), f2bf(acc[i][6]), f2bf(acc[i][7])};
            *reinterpret_cast<ushort4*>(Cb + (size_t)gr * 128 + c0) = b0;
            *reinterpret_cast<ushort4*>(Cb + (size_t)gr * 128 + c1) = b1;
        }
        float p1 = 0.f, p2 = 0.f;
#pragma unroll
        for (int j = 0; j < 8; ++j) {
            p1 += acc[i][j] * v1c[j];
            if (MODE == 1) p2 += acc[i][j] * v2c[j];
        }
#pragma unroll
        for (int off = 1; off < 16; off <<= 1) {
            p1 += __shfl_xor(p1, off, 16);
            if (MODE == 1) p2 += __shfl_xor(p2, off, 16);
        }
        if (tc == 0 && ok) {
            d1[gr] = p1;
            if (MODE == 1) d2[gr] = lrelu(p2);
        }
    }
}

// ---------------- tiny prep: asum = as[:128]+as[128:], wv = Wb @ c1 ----------------
__launch_bounds__(256)
__global__ void k_prep(const float* __restrict__ att_self, const float* __restrict__ att_cross,
                       const float* __restrict__ W_op, float* __restrict__ asum,
                       float* __restrict__ wv)
{
    int t = threadIdx.x;
    if (t < 128) asum[t] = att_self[t] + att_self[128 + t];
    if (t < 64) {
        float p = 0.f;
        const float* wr = W_op + (size_t)(DOPR + t) * 128;
#pragma unroll 16
        for (int j = 0; j < 128; ++j) p += wr[j] * att_cross[128 + j];
        wv[t] = p;
    }
}

// ---------------- edge scores + dst histogram: s[NMAT+e] = lrelu(dm[dst]+dop[src]+ea.wv) ----
__launch_bounds__(256)
__global__ void k_edge_score(const float* __restrict__ edge_attr,
                             const int* __restrict__ esrc, const int* __restrict__ edst,
                             const float* __restrict__ dm, const float* __restrict__ dop,
                             const float* __restrict__ wv, float* __restrict__ s,
                             int* __restrict__ cnt)
{
    int t = threadIdx.x;
    int g = t >> 4, q = t & 15;
    float4 wvq = *reinterpret_cast<const float4*>(wv + q * 4);
#pragma unroll
    for (int u = 0; u < 8; ++u) {
        int e = blockIdx.x * 128 + u * 16 + g;
        float4 av = *reinterpret_cast<const float4*>(edge_attr + (size_t)e * DEAT + q * 4);
        float p = av.x * wvq.x + av.y * wvq.y + av.z * wvq.z + av.w * wvq.w;
#pragma unroll
        for (int off = 1; off < 16; off <<= 1) p += __shfl_xor(p, off, 16);
        if (q == 0) {
            int d = edst[e];
            s[NMAT + e] = lrelu(p + dm[d] + dop[esrc[e]]);
            atomicAdd(&cnt[d], 1);
        }
    }
}

// ---------------- exclusive scan of cnt[NMAT] -> rowptr, cursor ----------------
__launch_bounds__(1024)
__global__ void k_scan(const int* __restrict__ cnt, int* __restrict__ rowptr,
                       int* __restrict__ cursor)
{
    __shared__ int sdata[1024];
    const int t = threadIdx.x;
    const int CH = 49;
    int base = t * CH;
    int lsum = 0;
#pragma unroll
    for (int j = 0; j < CH; ++j) {
        int idx = base + j;
        if (idx < NMAT) lsum += cnt[idx];
    }
    sdata[t] = lsum;
    __syncthreads();
    for (int off = 1; off < 1024; off <<= 1) {
        int v = (t >= off) ? sdata[t - off] : 0;
        __syncthreads();
        sdata[t] += v;
        __syncthreads();
    }
    int run = sdata[t] - lsum;
#pragma unroll
    for (int j = 0; j < CH; ++j) {
        int idx = base + j;
        if (idx < NMAT) {
            rowptr[idx] = run;
            cursor[idx] = run;
            run += cnt[idx];
        }
    }
    if (t == 1023) rowptr[NMAT] = NEDGE;
}

// ---------------- CSR fill ----------------
__launch_bounds__(256)
__global__ void k_fill(const int* __restrict__ edst, int* __restrict__ cursor,
                       int* __restrict__ eid)
{
    int e = blockIdx.x * 256 + threadIdx.x;
    if (e >= NEDGE) return;
    int pos = atomicAdd(&cursor[edst[e]], 1);
    eid[pos] = e;
}

// ---------------- global softmax reduction (online max+sumexp merge) ----------------
__launch_bounds__(256)
__global__ void softmax_red1(const float* __restrict__ s, float* __restrict__ part)
{
    const int n = NMAT + NEDGE;
    float mx = -INFINITY, sm = 0.f;
    for (int i = blockIdx.x * 256 + threadIdx.x; i < n; i += gridDim.x * 256) {
        float x = s[i];
        if (x > mx) { sm = sm * expf(mx - x) + 1.f; mx = x; }
        else        { sm += expf(x - mx); }
    }
#pragma unroll
    for (int off = 1; off < 64; off <<= 1) {
        float om = __shfl_xor(mx, off, 64);
        float os = __shfl_xor(sm, off, 64);
        float nm = fmaxf(mx, om);
        sm = sm * expf(mx - nm) + os * expf(om - nm);
        mx = nm;
    }
    __shared__ float wm[4], wsum[4];
    int lane = threadIdx.x & 63, wv = threadIdx.x >> 6;
    if (lane == 0) { wm[wv] = mx; wsum[wv] = sm; }
    __syncthreads();
    if (threadIdx.x == 0) {
        float M = wm[0], S = wsum[0];
        for (int i = 1; i < 4; ++i) {
            float nm = fmaxf(M, wm[i]);
            S = S * expf(M - nm) + wsum[i] * expf(wm[i] - nm);
            M = nm;
        }
        part[2 * blockIdx.x]     = M;
        part[2 * blockIdx.x + 1] = S;
    }
}

__launch_bounds__(256)
__global__ void softmax_red2(const float* __restrict__ part, float* __restrict__ stats)
{
    float mx = -INFINITY, sm = 0.f;
    for (int i = threadIdx.x; i < 1024; i += 256) {
        float M = part[2 * i], S = part[2 * i + 1];
        float nm = fmaxf(mx, M);
        sm = sm * expf(mx - nm) + S * expf(M - nm);
        mx = nm;
    }
#pragma unroll
    for (int off = 1; off < 64; off <<= 1) {
        float om = __shfl_xor(mx, off, 64);
        float os = __shfl_xor(sm, off, 64);
        float nm = fmaxf(mx, om);
        sm = sm * expf(mx - nm) + os * expf(om - nm);
        mx = nm;
    }
    __shared__ float wm[4], wsum[4];
    int lane = threadIdx.x & 63, wv = threadIdx.x >> 6;
    if (lane == 0) { wm[wv] = mx; wsum[wv] = sm; }
    __syncthreads();
    if (threadIdx.x == 0) {
        float M = wm[0], S = wsum[0];
        for (int i = 1; i < 4; ++i) {
            float nm = fmaxf(M, wm[i]);
            S = S * expf(M - nm) + wsum[i] * expf(wm[i] - nm);
            M = nm;
        }
        stats[0] = M;
        stats[1] = 1.f / S;
    }
}

// ---------------- CSR metadata: src_csr/w_csr in CSR order (breaks k_agg dep chain) -----
__launch_bounds__(256)
__global__ void k_csrmeta(const int* __restrict__ eid, const int* __restrict__ esrc,
                          const float* __restrict__ s, const float* __restrict__ stats,
                          int* __restrict__ src_csr, float* __restrict__ w_csr)
{
    int i = blockIdx.x * 256 + threadIdx.x;
    if (i >= NEDGE) return;
    int e = eid[i];
    src_csr[i] = esrc[e];
    w_csr[i] = expf(s[NMAT + e] - stats[0]) * stats[1];
}

// ---------------- CSR aggregate + fused epilogue ----------------
// wave per material, lane owns cols {2*lane, 2*lane+1}:
//   ap = sum w*opb[src] (bf16 gather), aw = sum w*ea_e ; out = elu(ns*m + ap + aw@Wb)
__launch_bounds__(256)
__global__ void k_agg(const unsigned short* __restrict__ opb, const float* __restrict__ m,
                      const float* __restrict__ edge_attr,
                      const int* __restrict__ eid, const int* __restrict__ src_csr,
                      const float* __restrict__ w_csr,
                      const float* __restrict__ W_op, const float* __restrict__ s,
                      const float* __restrict__ stats, const int* __restrict__ rowptr,
                      float* __restrict__ out)
{
    __shared__ float WbL[64][128];
    const int t = threadIdx.x;
#pragma unroll
    for (int it = 0; it < 8; ++it) {
        int q  = t + 256 * it;
        int kk = q >> 5, cc = (q & 31) * 4;
        *reinterpret_cast<float4*>(&WbL[kk][cc]) =
            *reinterpret_cast<const float4*>(W_op + (size_t)(DOPR + kk) * 128 + cc);
    }
    __syncthreads();

    const int w = t >> 6, lane = t & 63;
    const int mid = blockIdx.x * 4 + w;
    const float Mx = stats[0], invS = stats[1];
    const int beg = rowptr[mid], end = rowptr[mid + 1];

    float a0 = 0.f, a1 = 0.f, aw = 0.f;
    int base = beg;
    for (; base + 4 <= end; base += 4) {
        int e0 = eid[base], e1 = eid[base + 1], e2 = eid[base + 2], e3 = eid[base + 3];
        int s0 = src_csr[base], s1 = src_csr[base + 1];
        int s2 = src_csr[base + 2], s3 = src_csr[base + 3];
        float w0 = w_csr[base], w1 = w_csr[base + 1];
        float w2 = w_csr[base + 2], w3 = w_csr[base + 3];
        unsigned int o0 = *reinterpret_cast<const unsigned int*>(opb + (size_t)s0 * 128 + 2 * lane);
        unsigned int o1 = *reinterpret_cast<const unsigned int*>(opb + (size_t)s1 * 128 + 2 * lane);
        unsigned int o2 = *reinterpret_cast<const unsigned int*>(opb + (size_t)s2 * 128 + 2 * lane);
        unsigned int o3 = *reinterpret_cast<const unsigned int*>(opb + (size_t)s3 * 128 + 2 * lane);
        float q0 = edge_attr[(size_t)e0 * DEAT + lane];
        float q1 = edge_attr[(size_t)e1 * DEAT + lane];
        float q2 = edge_attr[(size_t)e2 * DEAT + lane];
        float q3 = edge_attr[(size_t)e3 * DEAT + lane];
        a0 += w0 * bflo(o0); a1 += w0 * bfhi(o0); aw += w0 * q0;
        a0 += w1 * bflo(o1); a1 += w1 * bfhi(o1); aw += w1 * q1;
        a0 += w2 * bflo(o2); a1 += w2 * bfhi(o2); aw += w2 * q2;
        a0 += w3 * bflo(o3); a1 += w3 * bfhi(o3); aw += w3 * q3;
    }
    for (; base < end; ++base) {
        int e = eid[base], src = src_csr[base];
        float wg = w_csr[base];
        unsigned int o = *reinterpret_cast<const unsigned int*>(opb + (size_t)src * 128 + 2 * lane);
        a0 += wg * bflo(o); a1 += wg * bfhi(o);
        aw += wg * edge_attr[(size_t)e * DEAT + lane];
    }

    float acc0 = a0, acc1 = a1;
#pragma unroll
    for (int k = 0; k < 64; ++k) {
        float awk = __shfl(aw, k, 64);
        float2 wb = *reinterpret_cast<const float2*>(&WbL[k][2 * lane]);
        acc0 += awk * wb.x;
        acc1 += awk * wb.y;
    }
    float ns = expf(s[mid] - Mx) * invS;
    float2 mv = *reinterpret_cast<const float2*>(m + (size_t)mid * 128 + 2 * lane);
    float2 r = {elu(ns * mv.x + acc0), elu(ns * mv.y + acc1)};
    *reinterpret_cast<float2*>(out + (size_t)mid * 128 + 2 * lane) = r;
}

extern "C" void kernel_launch(void* const* d_in, const int* in_sizes, int n_in,
                              void* d_out, int out_size, void* d_ws, size_t ws_size,
                              hipStream_t stream)
{
    const float* materials  = (const float*)d_in[0];
    const float* operations = (const float*)d_in[1];
    const float* edge_attr  = (const float*)d_in[2];
    const int*   esrc       = (const int*)d_in[3];
    const int*   edst       = (const int*)d_in[4];
    const float* W_mat      = (const float*)d_in[5];
    const float* W_op       = (const float*)d_in[6];
    const float* att_self   = (const float*)d_in[7];
    const float* att_cross  = (const float*)d_in[8];
    float* out = (float*)d_out;

    // workspace layout (~62 MB)
    float*          ws      = (float*)d_ws;
    float*          m_buf   = ws;                                    // 6,400,000 f
    unsigned short* opb     = (unsigned short*)(m_buf + (size_t)NMAT * 128);  // 12,800,000 us
    float*          s_buf   = (float*)(opb + (size_t)NOPS * 128);    // 562,000 f
    float*          dm      = s_buf + (NMAT + NEDGE);                // 50,000
    float*          dop     = dm + NMAT;                             // 100,000
    float*          asum    = dop + NOPS;                            // 128
    float*          wv      = asum + 128;                            // 64
    float*          part    = wv + 64;                               // 2048
    float*          stats   = part + 2048;                           // 2
    int*            cnt     = (int*)(stats + 2);                     // 50,000
    int*            rowptr  = cnt + NMAT;                            // 50,001
    int*            cursor  = rowptr + NMAT + 1;                     // 50,000
    int*            eid     = cursor + NMAT;                         // 512,000
    int*            src_csr = eid + NEDGE;                           // 512,000
    float*          w_csr   = (float*)(src_csr + NEDGE);             // 512,000

    hipMemsetAsync(cnt, 0, NMAT * sizeof(int), stream);

    k_prep<<<1, 256, 0, stream>>>(att_self, att_cross, W_op, asum, wv);
    gemm_rt<128, 1><<<(NMAT + 127) / 128, 256, 0, stream>>>(
        materials, W_mat, m_buf, nullptr, att_cross, asum, dm, s_buf, NMAT);
    gemm_rt<192, 2><<<(NOPS + 127) / 128, 256, 0, stream>>>(
        operations, W_op, nullptr, opb, att_cross + 128, nullptr, dop, nullptr, NOPS);
    k_edge_score<<<NEDGE / 128, 256, 0, stream>>>(edge_attr, esrc, edst, dm, dop, wv,
                                                  s_buf, cnt);
    k_scan<<<1, 1024, 0, stream>>>(cnt, rowptr, cursor);
    k_fill<<<NEDGE / 256, 256, 0, stream>>>(edst, cursor, eid);
    softmax_red1<<<1024, 256, 0, stream>>>(s_buf, part);
    softmax_red2<<<1, 256, 0, stream>>>(part, stats);
    k_csrmeta<<<NEDGE / 256, 256, 0, stream>>>(eid, esrc, s_buf, stats, src_csr, w_csr);
    k_agg<<<NMAT / 4, 256, 0, stream>>>(opb, m_buf, edge_attr, eid, src_csr, w_csr,
                                        W_op, s_buf, stats, rowptr, out);
}

// Round 4
// 399.012 us; speedup vs baseline: 2.9400x; 1.2274x over previous
//
#include <hip/hip_runtime.h>
#include <hip/hip_bf16.h>
#include <math.h>

#define NMAT  50000
#define NOPS  100000
#define NEDGE 512000
#define DOPR  192
#define DEAT  64

typedef __attribute__((ext_vector_type(8))) short bfx8;
typedef __attribute__((ext_vector_type(4))) float fx4;

static __device__ __forceinline__ float lrelu(float x) { return x > 0.f ? x : 0.2f * x; }
static __device__ __forceinline__ float elu(float x)   { return x > 0.f ? x : expm1f(x); }
static __device__ __forceinline__ unsigned short f2bf(float x) {
    unsigned int b = __float_as_uint(x);
    return (unsigned short)((b + 0x7fffu + ((b >> 16) & 1u)) >> 16);   // RNE
}
static __device__ __forceinline__ float bflo(unsigned int u) { return __uint_as_float(u << 16); }
static __device__ __forceinline__ float bfhi(unsigned int u) { return __uint_as_float(u & 0xffff0000u); }
static __device__ __forceinline__ float bf1(unsigned short u) { return __uint_as_float(((unsigned int)u) << 16); }

// ---------------- prep: folded score vectors (all fp32-exact) ----------------
// asum = as[:128]+as[128:]; wmc0 = W_mat@c0; wmas = W_mat@asum; woc1[k<192] = W_op@c1; wv = rows 192..255
__launch_bounds__(256)
__global__ void k_prep(const float* __restrict__ att_self, const float* __restrict__ att_cross,
                       const float* __restrict__ W_mat, const float* __restrict__ W_op,
                       float* __restrict__ asum, float* __restrict__ wv,
                       float* __restrict__ wmc0, float* __restrict__ wmas,
                       float* __restrict__ woc1)
{
    __shared__ float as_sh[128];
    int t = threadIdx.x;
    if (t < 128) { float v = att_self[t] + att_self[128 + t]; asum[t] = v; as_sh[t] = v; }
    __syncthreads();
    if (t < 128) {
        const float* wr = W_mat + (size_t)t * 128;
        float p0 = 0.f, p1 = 0.f;
        for (int j = 0; j < 128; ++j) { p0 += wr[j] * att_cross[j]; p1 += wr[j] * as_sh[j]; }
        wmc0[t] = p0; wmas[t] = p1;
    }
    {
        const float* wr = W_op + (size_t)t * 128;
        float p = 0.f;
        for (int j = 0; j < 128; ++j) p += wr[j] * att_cross[128 + j];
        if (t < DOPR) woc1[t] = p; else wv[t - DOPR] = p;
    }
}

// ---------------- convert weights to bf16 transposed: Bt[c][k] = B[k][c] ----------------
__launch_bounds__(256)
__global__ void k_conv(const float* __restrict__ W_mat, const float* __restrict__ W_op,
                       unsigned short* __restrict__ BtM, unsigned short* __restrict__ BtO)
{
    int id = blockIdx.x * 256 + threadIdx.x;
    if (id < 128 * 128) {
        int c = id >> 7, k = id & 127;
        BtM[c * 128 + k] = f2bf(W_mat[(size_t)k * 128 + c]);
    }
    if (id < 128 * DOPR) {
        int c = id / DOPR, k = id % DOPR;
        BtO[c * DOPR + k] = f2bf(W_op[(size_t)k * 128 + c]);
    }
}

// ---------------- MFMA GEMM: Cb[M][128] = bf16(A[M][K] @ B), fused fp32 row-dots ----------
// MODE 1: d1 = A.v1 (dm), d2 = lrelu(A.v2) (s_self).  MODE 2: d1 = A.v1 (dop).
template<int K, int MODE>
__launch_bounds__(256)
__global__ void gemm_mfma(const float* __restrict__ A, const unsigned short* __restrict__ Bt,
                          unsigned short* __restrict__ Cb,
                          const float* __restrict__ v1, const float* __restrict__ v2,
                          float* __restrict__ d1, float* __restrict__ d2, int M)
{
    __shared__ unsigned short As[128 * 40];   // [row][k], stride 40 (pad: ~2-way banks)
    __shared__ unsigned short Bs[128 * 40];   // [col][k]
    const int t = threadIdx.x;
    const int w = t >> 6, l = t & 63;
    const int lr = l & 15, lk = l >> 4;
    const int row0 = blockIdx.x * 128;

    fx4 acc[2][8];
#pragma unroll
    for (int i = 0; i < 2; ++i)
#pragma unroll
        for (int j = 0; j < 8; ++j) acc[i][j] = (fx4){0.f, 0.f, 0.f, 0.f};
    float pd1[4] = {0.f, 0.f, 0.f, 0.f};
    float pd2[4] = {0.f, 0.f, 0.f, 0.f};

    for (int k0 = 0; k0 < K; k0 += 32) {
#pragma unroll
        for (int it = 0; it < 4; ++it) {             // stage A (fp32 -> bf16) + dot partials
            int q  = t + 256 * it;
            int r  = q >> 3;
            int kk = (q & 7) * 4;
            int gr = row0 + r; if (gr >= M) gr = M - 1;
            float4 v = *reinterpret_cast<const float4*>(A + (size_t)gr * K + k0 + kk);
            ushort4 b = {f2bf(v.x), f2bf(v.y), f2bf(v.z), f2bf(v.w)};
            *reinterpret_cast<ushort4*>(&As[r * 40 + kk]) = b;
            pd1[it] += v.x * v1[k0 + kk] + v.y * v1[k0 + kk + 1]
                     + v.z * v1[k0 + kk + 2] + v.w * v1[k0 + kk + 3];
            if (MODE == 1)
                pd2[it] += v.x * v2[k0 + kk] + v.y * v2[k0 + kk + 1]
                         + v.z * v2[k0 + kk + 2] + v.w * v2[k0 + kk + 3];
        }
#pragma unroll
        for (int it = 0; it < 2; ++it) {             // stage B chunk (bf16, pre-transposed)
            int q  = t + 256 * it;
            int c  = q >> 2;
            int kg = (q & 3) * 8;
            uint4 vb = *reinterpret_cast<const uint4*>(&Bt[(size_t)c * K + k0 + kg]);
            *reinterpret_cast<uint4*>(&Bs[c * 40 + kg]) = vb;
        }
        __syncthreads();
        bfx8 af0 = *reinterpret_cast<const bfx8*>(&As[(w * 32 + lr) * 40 + lk * 8]);
        bfx8 af1 = *reinterpret_cast<const bfx8*>(&As[(w * 32 + 16 + lr) * 40 + lk * 8]);
#pragma unroll
        for (int ni = 0; ni < 8; ++ni) {
            bfx8 bf = *reinterpret_cast<const bfx8*>(&Bs[(ni * 16 + lr) * 40 + lk * 8]);
            acc[0][ni] = __builtin_amdgcn_mfma_f32_16x16x32_bf16(af0, bf, acc[0][ni], 0, 0, 0);
            acc[1][ni] = __builtin_amdgcn_mfma_f32_16x16x32_bf16(af1, bf, acc[1][ni], 0, 0, 0);
        }
        __syncthreads();
    }

    // C/D layout: col = lane&15, row = (lane>>4)*4 + reg
#pragma unroll
    for (int mi = 0; mi < 2; ++mi)
#pragma unroll
        for (int ni = 0; ni < 8; ++ni)
#pragma unroll
            for (int r2 = 0; r2 < 4; ++r2) {
                int row = row0 + w * 32 + mi * 16 + lk * 4 + r2;
                int col = ni * 16 + lr;
                if (row < M) Cb[(size_t)row * 128 + col] = f2bf(acc[mi][ni][r2]);
            }

    // fused row dots: 8 consecutive threads share one tile row
#pragma unroll
    for (int it = 0; it < 4; ++it) {
        float p1 = pd1[it], p2 = pd2[it];
#pragma unroll
        for (int off = 1; off < 8; off <<= 1) {
            p1 += __shfl_xor(p1, off, 8);
            if (MODE == 1) p2 += __shfl_xor(p2, off, 8);
        }
        int r  = (t + 256 * it) >> 3;
        int gr = row0 + r;
        if ((t & 7) == 0 && gr < M) {
            d1[gr] = p1;
            if (MODE == 1) d2[gr] = lrelu(p2);
        }
    }
}

// ---------------- edge scores + dst histogram (+ optional bf16 edge_attr copy) ----------
template<bool EA16>
__launch_bounds__(256)
__global__ void k_edge_score(const float* __restrict__ edge_attr,
                             const int* __restrict__ esrc, const int* __restrict__ edst,
                             const float* __restrict__ dm, const float* __restrict__ dop,
                             const float* __restrict__ wv, float* __restrict__ s,
                             int* __restrict__ cnt, unsigned short* __restrict__ eab)
{
    int t = threadIdx.x;
    int g = t >> 4, q = t & 15;
    float4 wvq = *reinterpret_cast<const float4*>(wv + q * 4);
#pragma unroll
    for (int u = 0; u < 8; ++u) {
        int e = blockIdx.x * 128 + u * 16 + g;
        float4 av = *reinterpret_cast<const float4*>(edge_attr + (size_t)e * DEAT + q * 4);
        if (EA16) {
            ushort4 bb = {f2bf(av.x), f2bf(av.y), f2bf(av.z), f2bf(av.w)};
            *reinterpret_cast<ushort4*>(&eab[(size_t)e * DEAT + q * 4]) = bb;
        }
        float p = av.x * wvq.x + av.y * wvq.y + av.z * wvq.z + av.w * wvq.w;
#pragma unroll
        for (int off = 1; off < 16; off <<= 1) p += __shfl_xor(p, off, 16);
        if (q == 0) {
            int d = edst[e];
            s[NMAT + e] = lrelu(p + dm[d] + dop[esrc[e]]);
            atomicAdd(&cnt[d], 1);
        }
    }
}

// ---------------- exclusive scan of cnt[NMAT] -> rowptr, cursor ----------------
__launch_bounds__(1024)
__global__ void k_scan(const int* __restrict__ cnt, int* __restrict__ rowptr,
                       int* __restrict__ cursor)
{
    __shared__ int sdata[1024];
    const int t = threadIdx.x;
    const int CH = 49;
    int base = t * CH;
    int lsum = 0;
#pragma unroll
    for (int j = 0; j < CH; ++j) {
        int idx = base + j;
        if (idx < NMAT) lsum += cnt[idx];
    }
    sdata[t] = lsum;
    __syncthreads();
    for (int off = 1; off < 1024; off <<= 1) {
        int v = (t >= off) ? sdata[t - off] : 0;
        __syncthreads();
        sdata[t] += v;
        __syncthreads();
    }
    int run = sdata[t] - lsum;
#pragma unroll
    for (int j = 0; j < CH; ++j) {
        int idx = base + j;
        if (idx < NMAT) {
            rowptr[idx] = run;
            cursor[idx] = run;
            run += cnt[idx];
        }
    }
    if (t == 1023) rowptr[NMAT] = NEDGE;
}

// ---------------- CSR fill ----------------
__launch_bounds__(256)
__global__ void k_fill(const int* __restrict__ edst, int* __restrict__ cursor,
                       int* __restrict__ eid)
{
    int e = blockIdx.x * 256 + threadIdx.x;
    if (e >= NEDGE) return;
    int pos = atomicAdd(&cursor[edst[e]], 1);
    eid[pos] = e;
}

// ---------------- global softmax reduction ----------------
__launch_bounds__(256)
__global__ void softmax_red1(const float* __restrict__ s, float* __restrict__ part)
{
    const int n = NMAT + NEDGE;
    float mx = -INFINITY, sm = 0.f;
    for (int i = blockIdx.x * 256 + threadIdx.x; i < n; i += gridDim.x * 256) {
        float x = s[i];
        if (x > mx) { sm = sm * expf(mx - x) + 1.f; mx = x; }
        else        { sm += expf(x - mx); }
    }
#pragma unroll
    for (int off = 1; off < 64; off <<= 1) {
        float om = __shfl_xor(mx, off, 64);
        float os = __shfl_xor(sm, off, 64);
        float nm = fmaxf(mx, om);
        sm = sm * expf(mx - nm) + os * expf(om - nm);
        mx = nm;
    }
    __shared__ float wm[4], wsum[4];
    int lane = threadIdx.x & 63, wv = threadIdx.x >> 6;
    if (lane == 0) { wm[wv] = mx; wsum[wv] = sm; }
    __syncthreads();
    if (threadIdx.x == 0) {
        float M = wm[0], S = wsum[0];
        for (int i = 1; i < 4; ++i) {
            float nm = fmaxf(M, wm[i]);
            S = S * expf(M - nm) + wsum[i] * expf(wm[i] - nm);
            M = nm;
        }
        part[2 * blockIdx.x]     = M;
        part[2 * blockIdx.x + 1] = S;
    }
}

__launch_bounds__(256)
__global__ void softmax_red2(const float* __restrict__ part, float* __restrict__ stats)
{
    float mx = -INFINITY, sm = 0.f;
    for (int i = threadIdx.x; i < 1024; i += 256) {
        float M = part[2 * i], S = part[2 * i + 1];
        float nm = fmaxf(mx, M);
        sm = sm * expf(mx - nm) + S * expf(M - nm);
        mx = nm;
    }
#pragma unroll
    for (int off = 1; off < 64; off <<= 1) {
        float om = __shfl_xor(mx, off, 64);
        float os = __shfl_xor(sm, off, 64);
        float nm = fmaxf(mx, om);
        sm = sm * expf(mx - nm) + os * expf(om - nm);
        mx = nm;
    }
    __shared__ float wm[4], wsum[4];
    int lane = threadIdx.x & 63, wv = threadIdx.x >> 6;
    if (lane == 0) { wm[wv] = mx; wsum[wv] = sm; }
    __syncthreads();
    if (threadIdx.x == 0) {
        float M = wm[0], S = wsum[0];
        for (int i = 1; i < 4; ++i) {
            float nm = fmaxf(M, wm[i]);
            S = S * expf(M - nm) + wsum[i] * expf(wm[i] - nm);
            M = nm;
        }
        stats[0] = M;
        stats[1] = 1.f / S;
    }
}

// ---------------- CSR metadata ----------------
__launch_bounds__(256)
__global__ void k_csrmeta(const int* __restrict__ eid, const int* __restrict__ esrc,
                          const float* __restrict__ s, const float* __restrict__ stats,
                          int* __restrict__ src_csr, float* __restrict__ w_csr)
{
    int i = blockIdx.x * 256 + threadIdx.x;
    if (i >= NEDGE) return;
    int e = eid[i];
    src_csr[i] = esrc[e];
    w_csr[i] = expf(s[NMAT + e] - stats[0]) * stats[1];
}

// ---------------- CSR aggregate + fused epilogue ----------------
// wave per material; lane owns opb/out cols {2l,2l+1} and ea col {l}
template<bool EA16>
__launch_bounds__(256)
__global__ void k_agg(const unsigned short* __restrict__ opb, const unsigned short* __restrict__ mb,
                      const unsigned short* __restrict__ eab, const float* __restrict__ edge_attr,
                      const int* __restrict__ eid, const int* __restrict__ src_csr,
                      const float* __restrict__ w_csr,
                      const float* __restrict__ W_op, const float* __restrict__ s,
                      const float* __restrict__ stats, const int* __restrict__ rowptr,
                      float* __restrict__ out)
{
    __shared__ unsigned int Wb2[64 * 64];   // packed bf16 pairs of W_op rows 192..255 (16 KB)
    const int t = threadIdx.x;
#pragma unroll
    for (int it = 0; it < 16; ++it) {
        int q = t + 256 * it;
        int k = q >> 6, c2 = q & 63;
        float2 v = *reinterpret_cast<const float2*>(W_op + (size_t)(DOPR + k) * 128 + 2 * c2);
        Wb2[q] = (unsigned int)f2bf(v.x) | ((unsigned int)f2bf(v.y) << 16);
    }
    __syncthreads();

    const int w = t >> 6, l = t & 63;
    const int mid = blockIdx.x * 4 + w;
    const float Mx = stats[0], invS = stats[1];
    const int beg = rowptr[mid], end = rowptr[mid + 1];

    float a0 = 0.f, a1 = 0.f, aw = 0.f;
    int base = beg;
    for (; base + 8 <= end; base += 8) {
        int ee[8], ss[8]; float ww[8];
#pragma unroll
        for (int u = 0; u < 8; ++u) {
            ee[u] = eid[base + u]; ss[u] = src_csr[base + u]; ww[u] = w_csr[base + u];
        }
        unsigned int o[8]; float ev[8];
#pragma unroll
        for (int u = 0; u < 8; ++u) {
            o[u] = *reinterpret_cast<const unsigned int*>(opb + (size_t)ss[u] * 128 + 2 * l);
            ev[u] = EA16 ? bf1(eab[(size_t)ee[u] * DEAT + l])
                         : edge_attr[(size_t)ee[u] * DEAT + l];
        }
#pragma unroll
        for (int u = 0; u < 8; ++u) {
            a0 += ww[u] * bflo(o[u]); a1 += ww[u] * bfhi(o[u]); aw += ww[u] * ev[u];
        }
    }
    for (; base < end; ++base) {
        int e = eid[base], src = src_csr[base];
        float wg = w_csr[base];
        unsigned int o = *reinterpret_cast<const unsigned int*>(opb + (size_t)src * 128 + 2 * l);
        float ev = EA16 ? bf1(eab[(size_t)e * DEAT + l]) : edge_attr[(size_t)e * DEAT + l];
        a0 += wg * bflo(o); a1 += wg * bfhi(o); aw += wg * ev;
    }

    float acc0 = a0, acc1 = a1;
#pragma unroll
    for (int k = 0; k < 64; ++k) {
        float awk = __shfl(aw, k, 64);
        unsigned int wb = Wb2[k * 64 + l];
        acc0 += awk * bflo(wb);
        acc1 += awk * bfhi(wb);
    }
    float ns = expf(s[mid] - Mx) * invS;
    unsigned int mv = *reinterpret_cast<const unsigned int*>(mb + (size_t)mid * 128 + 2 * l);
    float2 r = {elu(ns * bflo(mv) + acc0), elu(ns * bfhi(mv) + acc1)};
    *reinterpret_cast<float2*>(out + (size_t)mid * 128 + 2 * l) = r;
}

extern "C" void kernel_launch(void* const* d_in, const int* in_sizes, int n_in,
                              void* d_out, int out_size, void* d_ws, size_t ws_size,
                              hipStream_t stream)
{
    const float* materials  = (const float*)d_in[0];
    const float* operations = (const float*)d_in[1];
    const float* edge_attr  = (const float*)d_in[2];
    const int*   esrc       = (const int*)d_in[3];
    const int*   edst       = (const int*)d_in[4];
    const float* W_mat      = (const float*)d_in[5];
    const float* W_op       = (const float*)d_in[6];
    const float* att_self   = (const float*)d_in[7];
    const float* att_cross  = (const float*)d_in[8];
    float* out = (float*)d_out;

    char* p = (char*)d_ws;
    auto take = [&](size_t bytes) { char* r = p; p += (bytes + 255) & ~(size_t)255; return r; };

    unsigned short* mb      = (unsigned short*)take((size_t)NMAT * 128 * 2);
    unsigned short* opb     = (unsigned short*)take((size_t)NOPS * 128 * 2);
    float*          s_buf   = (float*)take((size_t)(NMAT + NEDGE) * 4);
    float*          dm      = (float*)take((size_t)NMAT * 4);
    float*          dop     = (float*)take((size_t)NOPS * 4);
    float*          asum    = (float*)take(128 * 4);
    float*          wv      = (float*)take(64 * 4);
    float*          wmc0    = (float*)take(128 * 4);
    float*          wmas    = (float*)take(128 * 4);
    float*          woc1    = (float*)take(DOPR * 4);
    unsigned short* BtM     = (unsigned short*)take(128 * 128 * 2);
    unsigned short* BtO     = (unsigned short*)take(128 * DOPR * 2);
    float*          part    = (float*)take(2048 * 4);
    float*          stats   = (float*)take(2 * 4);
    int*            cnt     = (int*)take((size_t)NMAT * 4);
    int*            rowptr  = (int*)take((size_t)(NMAT + 1) * 4);
    int*            cursor  = (int*)take((size_t)NMAT * 4);
    int*            eid     = (int*)take((size_t)NEDGE * 4);
    int*            src_csr = (int*)take((size_t)NEDGE * 4);
    float*          w_csr   = (float*)take((size_t)NEDGE * 4);
    unsigned short* eab     = (unsigned short*)take((size_t)NEDGE * DEAT * 2);
    bool useEab = ((size_t)(p - (char*)d_ws) <= ws_size);

    hipMemsetAsync(cnt, 0, NMAT * sizeof(int), stream);

    k_prep<<<1, 256, 0, stream>>>(att_self, att_cross, W_mat, W_op,
                                  asum, wv, wmc0, wmas, woc1);
    k_conv<<<96, 256, 0, stream>>>(W_mat, W_op, BtM, BtO);
    gemm_mfma<128, 1><<<(NMAT + 127) / 128, 256, 0, stream>>>(
        materials, BtM, mb, wmc0, wmas, dm, s_buf, NMAT);
    gemm_mfma<192, 2><<<(NOPS + 127) / 128, 256, 0, stream>>>(
        operations, BtO, opb, woc1, nullptr, dop, nullptr, NOPS);
    if (useEab)
        k_edge_score<true><<<NEDGE / 128, 256, 0, stream>>>(edge_attr, esrc, edst, dm, dop,
                                                            wv, s_buf, cnt, eab);
    else
        k_edge_score<false><<<NEDGE / 128, 256, 0, stream>>>(edge_attr, esrc, edst, dm, dop,
                                                             wv, s_buf, cnt, nullptr);
    k_scan<<<1, 1024, 0, stream>>>(cnt, rowptr, cursor);
    k_fill<<<NEDGE / 256, 256, 0, stream>>>(edst, cursor, eid);
    softmax_red1<<<1024, 256, 0, stream>>>(s_buf, part);
    softmax_red2<<<1, 256, 0, stream>>>(part, stats);
    k_csrmeta<<<NEDGE / 256, 256, 0, stream>>>(eid, esrc, s_buf, stats, src_csr, w_csr);
    if (useEab)
        k_agg<true><<<NMAT / 4, 256, 0, stream>>>(opb, mb, eab, edge_attr, eid, src_csr,
                                                  w_csr, W_op, s_buf, stats, rowptr, out);
    else
        k_agg<false><<<NMAT / 4, 256, 0, stream>>>(opb, mb, nullptr, edge_attr, eid, src_csr,
                                                   w_csr, W_op, s_buf, stats, rowptr, out);
}